// Round 2
// baseline (3722.894 us; speedup 1.0000x reference)
//
#include <hip/hip_runtime.h>
#include <cstdint>
#include <cstddef>

#define D_MODEL   3072
#define D_SPARSE  24576
#define N_TOKENS  8192
#define K_SPARSE  128

typedef _Float16 half8  __attribute__((ext_vector_type(8)));
typedef _Float16 half4v __attribute__((ext_vector_type(4)));
typedef float    f32x4  __attribute__((ext_vector_type(4)));

// Power-of-2 scales keep fp16 values away from subnormals; exactly undone in epilogue.
#define SCALE_A   64.0f
#define SCALE_B   4096.0f
#define INV_SCALE (1.0f/(SCALE_A*SCALE_B))   // 2^-18, exact

// Classification window half-width for the exact-rescue pass.
// Max approx deviation (fp16 quantization of both operands, K=3072) is ~1.2e-3;
// requirement is DELTA >= 2*max_dev. 6e-3 gives 2.5x headroom.
#define DELTA 6.0e-3f
#define MAXU  256

#define GLOBAL_AS(p) ((const __attribute__((address_space(1))) uint32_t*)(p))
#define LDS_AS(p)    ((__attribute__((address_space(3))) uint32_t*)(p))

// ---------- converts: fp32 -> fp16 (single hi limb), scaled ----------
__global__ void convert_h_kernel(const float* __restrict__ h,
                                 const float* __restrict__ pre_bias,
                                 _Float16* __restrict__ A1) {
  const int total4 = N_TOKENS * (D_MODEL/4);
  for (int m = blockIdx.x*blockDim.x + threadIdx.x; m < total4; m += gridDim.x*blockDim.x) {
    const int c4 = m % (D_MODEL/4);
    const float4 v  = reinterpret_cast<const float4*>(h)[m];
    const float4 pb = reinterpret_cast<const float4*>(pre_bias)[c4];
    half4v o;
    o[0] = (_Float16)((v.x-pb.x)*SCALE_A); o[1] = (_Float16)((v.y-pb.y)*SCALE_A);
    o[2] = (_Float16)((v.z-pb.z)*SCALE_A); o[3] = (_Float16)((v.w-pb.w)*SCALE_A);
    reinterpret_cast<half4v*>(A1)[m] = o;
  }
}

__global__ void convert_w_kernel(const float* __restrict__ W,
                                 _Float16* __restrict__ B1) {
  const int total4 = D_SPARSE * (D_MODEL/4);
  for (int m = blockIdx.x*blockDim.x + threadIdx.x; m < total4; m += gridDim.x*blockDim.x) {
    const float4 v = reinterpret_cast<const float4*>(W)[m];
    half4v o;
    o[0] = (_Float16)(v.x*SCALE_B); o[1] = (_Float16)(v.y*SCALE_B);
    o[2] = (_Float16)(v.z*SCALE_B); o[3] = (_Float16)(v.w*SCALE_B);
    reinterpret_cast<half4v*>(B1)[m] = o;
  }
}

// ---------- GEMM: C[n,s] = (A1 . B1^T) * 2^-18 + enc_bias ----------
// m97 structure: 128x128 tile, BK=32, 4 waves (2x2), 4x4 frags of 16x16x32_f16,
// global_load_lds width-16 staging, 2 barriers per K-step.
#define BM 128
#define BN 128
#define BK 32

__global__ __launch_bounds__(256) void gemm_kernel(const _Float16* __restrict__ A1,
                                                   const _Float16* __restrict__ B1,
                                                   const float* __restrict__ enc_bias,
                                                   float* __restrict__ C) {
  __shared__ _Float16 As[BM][BK];   // 8 KB
  __shared__ _Float16 Bs[BN][BK];   // 8 KB

  const int nBlkN = D_SPARSE / BN;  // 192
  const int SW = 8;                 // supertile for L2/L3 reuse
  const int bid   = blockIdx.x;
  const int group = bid / (SW * nBlkN);
  const int rem   = bid % (SW * nBlkN);
  const int bm = group * SW + (rem % SW);   // 0..63
  const int bn = rem / SW;                  // 0..191

  const int tid  = threadIdx.x;
  const int lane = tid & 63;
  const int wid  = tid >> 6;
  const int wm = wid >> 1, wn = wid & 1;

  const _Float16* gA = A1 + (size_t)bm * BM * D_MODEL;
  const _Float16* gB = B1 + (size_t)bn * BN * D_MODEL;

  f32x4 acc[4][4] = {};

  const int r16   = lane & 15;
  const int khalf = lane >> 4;

  const int c0 = wid*64 + lane;
  const int c1 = c0 + 256;
  const int rA0 = c0 >> 2, sA0 = (c0 & 3) * 8;
  const int rA1 = c1 >> 2, sA1 = (c1 & 3) * 8;
  _Float16* const la0 = &As[0][0] + (wid*64      )*8;
  _Float16* const la1 = &As[0][0] + (wid*64 + 256)*8;
  _Float16* const lb0 = &Bs[0][0] + (wid*64      )*8;
  _Float16* const lb1 = &Bs[0][0] + (wid*64 + 256)*8;

  #pragma unroll 1
  for (int kc = 0; kc < D_MODEL/BK; ++kc) {   // 96 steps
    const int col = kc*BK;
    __builtin_amdgcn_global_load_lds(GLOBAL_AS(gA + (size_t)rA0*D_MODEL + col + sA0), LDS_AS(la0), 16, 0, 0);
    __builtin_amdgcn_global_load_lds(GLOBAL_AS(gA + (size_t)rA1*D_MODEL + col + sA1), LDS_AS(la1), 16, 0, 0);
    __builtin_amdgcn_global_load_lds(GLOBAL_AS(gB + (size_t)rA0*D_MODEL + col + sA0), LDS_AS(lb0), 16, 0, 0);
    __builtin_amdgcn_global_load_lds(GLOBAL_AS(gB + (size_t)rA1*D_MODEL + col + sA1), LDS_AS(lb1), 16, 0, 0);

    __syncthreads();

    half8 af[4], bf[4];
    #pragma unroll
    for (int mi=0; mi<4; ++mi) af[mi] = *reinterpret_cast<const half8*>(&As[wm*64 + mi*16 + r16][khalf*8]);
    #pragma unroll
    for (int ni=0; ni<4; ++ni) bf[ni] = *reinterpret_cast<const half8*>(&Bs[wn*64 + ni*16 + r16][khalf*8]);
    #pragma unroll
    for (int mi=0; mi<4; ++mi)
      #pragma unroll
      for (int ni=0; ni<4; ++ni)
        acc[mi][ni] = __builtin_amdgcn_mfma_f32_16x16x32_f16(af[mi], bf[ni], acc[mi][ni], 0, 0, 0);

    __syncthreads();
  }

  // C/D layout: col=lane&15, row=(lane>>4)*4+reg [m89-verified, dtype-independent]
  #pragma unroll
  for (int mi=0; mi<4; ++mi) {
    const int row = bm*BM + wm*64 + mi*16 + khalf*4;
    #pragma unroll
    for (int ni=0; ni<4; ++ni) {
      const int col = bn*BN + wn*64 + ni*16 + r16;
      const float b = enc_bias[col];
      #pragma unroll
      for (int r=0; r<4; ++r)
        C[(size_t)(row + r) * D_SPARSE + col] = acc[mi][ni][r] * INV_SCALE + b;
    }
  }
}

// ---------- top-k with exact fp64 rescue at the rank boundary ----------
__device__ __forceinline__ uint32_t f2key(float f) {
  uint32_t b = __float_as_uint(f);
  return (b & 0x80000000u) ? ~b : (b | 0x80000000u);
}
__device__ __forceinline__ float key2f(uint32_t k) {
  uint32_t b = (k & 0x80000000u) ? (k ^ 0x80000000u) : ~k;
  return __uint_as_float(b);
}

__global__ __launch_bounds__(256) void topk_kernel(float* __restrict__ C,
                                                   const float* __restrict__ h,
                                                   const float* __restrict__ pre_bias,
                                                   const float* __restrict__ W,
                                                   const float* __restrict__ enc_bias) {
  const int row = blockIdx.x;
  float* __restrict__ Crow = C + (size_t)row * D_SPARSE;
  const int tid = threadIdx.x;

  __shared__ int hist[256];
  __shared__ int s_digit, s_rem;
  __shared__ int s_nabove, s_ucnt;
  __shared__ int u_idx[MAXU];
  __shared__ double u_val[MAXU];
  __shared__ unsigned char u_sel[MAXU];
  __shared__ double red[4];

  uint32_t key[96];
  #pragma unroll
  for (int j = 0; j < 24; ++j) {
    const float4 v = reinterpret_cast<const float4*>(Crow)[tid + j*256];
    key[j*4+0] = f2key(v.x); key[j*4+1] = f2key(v.y);
    key[j*4+2] = f2key(v.z); key[j*4+3] = f2key(v.w);
  }

  // 4-level MSB radix select -> prefix = key of approx 128th-largest
  uint32_t prefix = 0, pmask = 0;
  int remaining = K_SPARSE;
  for (int level = 0; level < 4; ++level) {
    const int shift = 24 - 8*level;
    hist[tid] = 0;
    __syncthreads();
    #pragma unroll
    for (int j = 0; j < 96; ++j) {
      const uint32_t k = key[j];
      if ((k & pmask) == prefix) atomicAdd(&hist[(k >> shift) & 255], 1);
    }
    __syncthreads();
    if (tid == 0) {
      int cum = 0, b = 255;
      for (; b >= 0; --b) { const int c = hist[b]; if (cum + c >= remaining) break; cum += c; }
      if (b < 0) b = 0;
      s_digit = b; s_rem = remaining - cum;
    }
    __syncthreads();
    prefix |= ((uint32_t)s_digit) << shift;
    pmask  |= (0xFFu << shift);
    remaining = s_rem;
    __syncthreads();
  }

  const float kth   = key2f(prefix);
  const float thrHi = kth + DELTA;
  const float thrLo = kth - DELTA;

  if (tid == 0) { s_nabove = 0; s_ucnt = 0; }
  __syncthreads();

  int myAbove = 0;
  #pragma unroll
  for (int j = 0; j < 96; ++j) {
    const float v = key2f(key[j]);
    if (v > thrHi) myAbove++;
    else if (v >= thrLo) {
      const int p = atomicAdd(&s_ucnt, 1);
      if (p < MAXU) u_idx[p] = ((tid + ((j >> 2) << 8)) << 2) + (j & 3);
    }
  }
  atomicAdd(&s_nabove, myAbove);
  __syncthreads();

  const int ucnt = s_ucnt < MAXU ? s_ucnt : MAXU;
  int m = K_SPARSE - s_nabove;
  if (m < 0) m = 0; if (m > ucnt) m = ucnt;

  // exact fp64 dots for the in-window candidates (whole block per candidate)
  const float* hrow = h + (size_t)row * D_MODEL;
  for (int e = 0; e < ucnt; ++e) {
    const int ci = u_idx[e];
    const float* wrow = W + (size_t)ci * D_MODEL;
    double s = 0.0;
    for (int k = tid; k < D_MODEL; k += 256)
      s += (double)(hrow[k] - pre_bias[k]) * (double)wrow[k];
    #pragma unroll
    for (int off = 32; off; off >>= 1) s += __shfl_down(s, off, 64);
    if ((tid & 63) == 0) red[tid >> 6] = s;
    __syncthreads();
    if (tid == 0) u_val[e] = (red[0]+red[1]+red[2]+red[3]) + (double)enc_bias[ci];
    __syncthreads();
  }

  // pick top-m of candidates by (exact value desc, index asc) — jax tiebreak
  if (tid == 0) {
    for (int e = 0; e < ucnt; ++e) u_sel[e] = 0;
    for (int t = 0; t < m; ++t) {
      int best = -1;
      for (int e = 0; e < ucnt; ++e) {
        if (u_sel[e]) continue;
        if (best < 0 || u_val[e] > u_val[best] ||
            (u_val[e] == u_val[best] && u_idx[e] < u_idx[best])) best = e;
      }
      if (best >= 0) u_sel[best] = 1;
    }
  }
  __syncthreads();

  // bulk write: sure-keeps get relu(approx), everything else 0
  #pragma unroll
  for (int j = 0; j < 24; ++j) {
    float4 out;
    #pragma unroll
    for (int c = 0; c < 4; ++c) {
      const float v = key2f(key[j*4+c]);
      (&out.x)[c] = (v > thrHi) ? fmaxf(v, 0.0f) : 0.0f;
    }
    reinterpret_cast<float4*>(Crow)[tid + j*256] = out;
  }
  __syncthreads();

  // overwrite selected candidates with relu(exact)
  for (int e = tid; e < ucnt; e += 256)
    if (u_sel[e]) Crow[u_idx[e]] = fmaxf((float)u_val[e], 0.0f);
}

// ---------------------------------------------------------------------------
extern "C" void kernel_launch(void* const* d_in, const int* in_sizes, int n_in,
                              void* d_out, int out_size, void* d_ws, size_t ws_size,
                              hipStream_t stream) {
  const float* h        = (const float*)d_in[0];
  const float* W        = (const float*)d_in[1];
  const float* pre_bias = (const float*)d_in[2];
  const float* enc_bias = (const float*)d_in[3];
  float* C = (float*)d_out;

  const size_t a1_bytes = (size_t)N_TOKENS * D_MODEL * sizeof(_Float16);   // 50.3 MB
  const size_t b1_bytes = (size_t)D_SPARSE * D_MODEL * sizeof(_Float16);   // 151.0 MB
  if (ws_size < a1_bytes + b1_bytes) return;

  _Float16* A1 = (_Float16*)d_ws;
  _Float16* B1 = (_Float16*)((char*)d_ws + a1_bytes);

  convert_h_kernel<<<2048, 256, 0, stream>>>(h, pre_bias, A1);
  convert_w_kernel<<<4096, 256, 0, stream>>>(W, B1);
  gemm_kernel<<<(N_TOKENS/BM) * (D_SPARSE/BN), 256, 0, stream>>>(A1, B1, enc_bias, C);
  topk_kernel<<<N_TOKENS, 256, 0, stream>>>(C, h, pre_bias, W, enc_bias);
}

// Round 3
// 3485.780 us; speedup vs baseline: 1.0680x; 1.0680x over previous
//
#include <hip/hip_runtime.h>
#include <cstdint>
#include <cstddef>

#define D_MODEL   3072
#define D_SPARSE  24576
#define N_TOKENS  8192
#define K_SPARSE  128

typedef _Float16 half8  __attribute__((ext_vector_type(8)));
typedef _Float16 half4v __attribute__((ext_vector_type(4)));
typedef float    f32x4  __attribute__((ext_vector_type(4)));

// Power-of-2 scales keep fp16 values away from subnormals; exactly undone in epilogue.
#define SCALE_A   64.0f
#define SCALE_B   4096.0f
#define INV_SCALE (1.0f/(SCALE_A*SCALE_B))   // 2^-18, exact

// Classification window half-width for the exact-rescue pass.
// fp16 quantization dev for K=3072 dot: sigma ~ 7e-4, DELTA = 6e-3 ~ 9 sigma.
#define DELTA 6.0e-3f
#define MAXU  256

#define GLOBAL_AS(p) ((const __attribute__((address_space(1))) uint32_t*)(p))
#define LDS_AS(p)    ((__attribute__((address_space(3))) uint32_t*)(p))

// ---------- converts: fp32 -> fp16 (single hi limb), scaled ----------
__global__ void convert_h_kernel(const float* __restrict__ h,
                                 const float* __restrict__ pre_bias,
                                 _Float16* __restrict__ A1) {
  const int total4 = N_TOKENS * (D_MODEL/4);
  for (int m = blockIdx.x*blockDim.x + threadIdx.x; m < total4; m += gridDim.x*blockDim.x) {
    const int c4 = m % (D_MODEL/4);
    const float4 v  = reinterpret_cast<const float4*>(h)[m];
    const float4 pb = reinterpret_cast<const float4*>(pre_bias)[c4];
    half4v o;
    o[0] = (_Float16)((v.x-pb.x)*SCALE_A); o[1] = (_Float16)((v.y-pb.y)*SCALE_A);
    o[2] = (_Float16)((v.z-pb.z)*SCALE_A); o[3] = (_Float16)((v.w-pb.w)*SCALE_A);
    reinterpret_cast<half4v*>(A1)[m] = o;
  }
}

__global__ void convert_w_kernel(const float* __restrict__ W,
                                 _Float16* __restrict__ B1) {
  const int total4 = D_SPARSE * (D_MODEL/4);
  for (int m = blockIdx.x*blockDim.x + threadIdx.x; m < total4; m += gridDim.x*blockDim.x) {
    const float4 v = reinterpret_cast<const float4*>(W)[m];
    half4v o;
    o[0] = (_Float16)(v.x*SCALE_B); o[1] = (_Float16)(v.y*SCALE_B);
    o[2] = (_Float16)(v.z*SCALE_B); o[3] = (_Float16)(v.w*SCALE_B);
    reinterpret_cast<half4v*>(B1)[m] = o;
  }
}

// ---------- GEMM: C[n,s] = (A1 . B1^T) * 2^-18 + enc_bias ----------
#define BM 128
#define BN 128
#define BK 32

__global__ __launch_bounds__(256) void gemm_kernel(const _Float16* __restrict__ A1,
                                                   const _Float16* __restrict__ B1,
                                                   const float* __restrict__ enc_bias,
                                                   float* __restrict__ C) {
  __shared__ _Float16 As[BM][BK];
  __shared__ _Float16 Bs[BN][BK];

  const int nBlkN = D_SPARSE / BN;  // 192
  const int SW = 8;
  const int bid   = blockIdx.x;
  const int group = bid / (SW * nBlkN);
  const int rem   = bid % (SW * nBlkN);
  const int bm = group * SW + (rem % SW);
  const int bn = rem / SW;

  const int tid  = threadIdx.x;
  const int lane = tid & 63;
  const int wid  = tid >> 6;
  const int wm = wid >> 1, wn = wid & 1;

  const _Float16* gA = A1 + (size_t)bm * BM * D_MODEL;
  const _Float16* gB = B1 + (size_t)bn * BN * D_MODEL;

  f32x4 acc[4][4] = {};

  const int r16   = lane & 15;
  const int khalf = lane >> 4;

  const int c0 = wid*64 + lane;
  const int c1 = c0 + 256;
  const int rA0 = c0 >> 2, sA0 = (c0 & 3) * 8;
  const int rA1 = c1 >> 2, sA1 = (c1 & 3) * 8;
  _Float16* const la0 = &As[0][0] + (wid*64      )*8;
  _Float16* const la1 = &As[0][0] + (wid*64 + 256)*8;
  _Float16* const lb0 = &Bs[0][0] + (wid*64      )*8;
  _Float16* const lb1 = &Bs[0][0] + (wid*64 + 256)*8;

  #pragma unroll 1
  for (int kc = 0; kc < D_MODEL/BK; ++kc) {
    const int col = kc*BK;
    __builtin_amdgcn_global_load_lds(GLOBAL_AS(gA + (size_t)rA0*D_MODEL + col + sA0), LDS_AS(la0), 16, 0, 0);
    __builtin_amdgcn_global_load_lds(GLOBAL_AS(gA + (size_t)rA1*D_MODEL + col + sA1), LDS_AS(la1), 16, 0, 0);
    __builtin_amdgcn_global_load_lds(GLOBAL_AS(gB + (size_t)rA0*D_MODEL + col + sA0), LDS_AS(lb0), 16, 0, 0);
    __builtin_amdgcn_global_load_lds(GLOBAL_AS(gB + (size_t)rA1*D_MODEL + col + sA1), LDS_AS(lb1), 16, 0, 0);

    __syncthreads();

    half8 af[4], bf[4];
    #pragma unroll
    for (int mi=0; mi<4; ++mi) af[mi] = *reinterpret_cast<const half8*>(&As[wm*64 + mi*16 + r16][khalf*8]);
    #pragma unroll
    for (int ni=0; ni<4; ++ni) bf[ni] = *reinterpret_cast<const half8*>(&Bs[wn*64 + ni*16 + r16][khalf*8]);
    #pragma unroll
    for (int mi=0; mi<4; ++mi)
      #pragma unroll
      for (int ni=0; ni<4; ++ni)
        acc[mi][ni] = __builtin_amdgcn_mfma_f32_16x16x32_f16(af[mi], bf[ni], acc[mi][ni], 0, 0, 0);

    __syncthreads();
  }

  #pragma unroll
  for (int mi=0; mi<4; ++mi) {
    const int row = bm*BM + wm*64 + mi*16 + khalf*4;
    #pragma unroll
    for (int ni=0; ni<4; ++ni) {
      const int col = bn*BN + wn*64 + ni*16 + r16;
      const float b = enc_bias[col];
      #pragma unroll
      for (int r=0; r<4; ++r)
        C[(size_t)(row + r) * D_SPARSE + col] = acc[mi][ni][r] * INV_SCALE + b;
    }
  }
}

// ---------- top-k with exact fp64 rescue at the rank boundary ----------
__device__ __forceinline__ uint32_t f2key(float f) {
  uint32_t b = __float_as_uint(f);
  return (b & 0x80000000u) ? ~b : (b | 0x80000000u);
}
__device__ __forceinline__ float key2f(uint32_t k) {
  uint32_t b = (k & 0x80000000u) ? (k ^ 0x80000000u) : ~k;
  return __uint_as_float(b);
}

__global__ __launch_bounds__(256) void topk_kernel(float* __restrict__ C,
                                                   const float* __restrict__ h,
                                                   const float* __restrict__ pre_bias,
                                                   const float* __restrict__ W,
                                                   const float* __restrict__ enc_bias) {
  const int row = blockIdx.x;
  float* __restrict__ Crow = C + (size_t)row * D_SPARSE;
  const int tid  = threadIdx.x;
  const int lane = tid & 63;
  const int wid  = tid >> 6;

  __shared__ int hist4[4][256];     // per-wave sub-histograms (cuts same-address serialization)
  __shared__ int wsum[4];
  __shared__ int s_found, s_digit, s_rem;
  __shared__ int s_above0, s_nabove, s_ucnt;
  __shared__ int u_idx[MAXU];
  __shared__ double u_val[MAXU];
  __shared__ unsigned char u_sel[MAXU];

  uint32_t key[96];
  #pragma unroll
  for (int j = 0; j < 24; ++j) {
    const float4 v = reinterpret_cast<const float4*>(Crow)[tid + j*256];
    key[j*4+0] = f2key(v.x); key[j*4+1] = f2key(v.y);
    key[j*4+2] = f2key(v.z); key[j*4+3] = f2key(v.w);
  }

  // --- prefilter: if >=128 values exceed 2.0, only histogram those (exact; fallback otherwise)
  const uint32_t k0 = f2key(2.0f);
  int myc = 0;
  #pragma unroll
  for (int j = 0; j < 96; ++j) myc += (key[j] > k0) ? 1 : 0;
  if (tid == 0) s_above0 = 0;
  __syncthreads();
  atomicAdd(&s_above0, myc);
  __syncthreads();
  const uint32_t kmin = (s_above0 >= K_SPARSE) ? (k0 + 1u) : 0u;

  // --- 4-level MSB radix select with parallel scan digit-pick
  uint32_t prefix = 0, pmask = 0;
  int remaining = K_SPARSE;
  for (int level = 0; level < 4; ++level) {
    const int shift = 24 - 8*level;
    #pragma unroll
    for (int w = 0; w < 4; ++w) hist4[w][tid] = 0;
    __syncthreads();
    #pragma unroll
    for (int j = 0; j < 96; ++j) {
      const uint32_t k = key[j];
      if (k >= kmin && (k & pmask) == prefix)
        atomicAdd(&hist4[wid][(k >> shift) & 255], 1);
    }
    if (tid == 0) s_found = 1 << 30;
    __syncthreads();

    const int bin = 255 - tid;                     // descending bins
    const int cnt = hist4[0][bin] + hist4[1][bin] + hist4[2][bin] + hist4[3][bin];
    int sc = cnt;                                  // inclusive scan (from top bin down)
    #pragma unroll
    for (int d = 1; d < 64; d <<= 1) {
      const int o = __shfl_up(sc, d, 64);
      if (lane >= d) sc += o;
    }
    if (lane == 63) wsum[wid] = sc;
    __syncthreads();
    int woff = 0;
    for (int w = 0; w < wid; ++w) woff += wsum[w];
    sc += woff;
    if (sc >= remaining) atomicMin(&s_found, tid); // first crossing (highest bin)
    __syncthreads();
    if (tid == s_found) { s_digit = bin; s_rem = remaining - (sc - cnt); }
    __syncthreads();
    prefix |= ((uint32_t)s_digit) << shift;
    pmask  |= 0xFFu << shift;
    remaining = s_rem;
    __syncthreads();
  }

  const float kth   = key2f(prefix);               // approx 128th-largest value
  const float thrHi = kth + DELTA;
  const float thrLo = kth - DELTA;

  if (tid == 0) { s_nabove = 0; s_ucnt = 0; }
  __syncthreads();

  int myAbove = 0;
  #pragma unroll
  for (int j = 0; j < 96; ++j) {
    const float v = key2f(key[j]);
    if (v > thrHi) myAbove++;
    else if (v >= thrLo) {
      const int p = atomicAdd(&s_ucnt, 1);
      if (p < MAXU) u_idx[p] = ((tid + ((j >> 2) << 8)) << 2) + (j & 3);
    }
  }
  atomicAdd(&s_nabove, myAbove);
  __syncthreads();

  const int ucnt = s_ucnt < MAXU ? s_ucnt : MAXU;
  int m = K_SPARSE - s_nabove;
  if (m < 0) m = 0; if (m > ucnt) m = ucnt;

  // --- exact fp64 dots, one WAVE per candidate (no block barriers inside)
  const float* hrow = h + (size_t)row * D_MODEL;
  for (int e = wid; e < ucnt; e += 4) {
    const int ci = u_idx[e];
    const float* wrow = W + (size_t)ci * D_MODEL;
    double s = 0.0;
    for (int k = lane; k < D_MODEL; k += 64)
      s += (double)(hrow[k] - pre_bias[k]) * (double)wrow[k];
    #pragma unroll
    for (int off = 32; off; off >>= 1) s += __shfl_down(s, off, 64);
    if (lane == 0) u_val[e] = s + (double)enc_bias[ci];
  }
  __syncthreads();

  // --- pick top-m candidates by (exact value desc, index asc) — jax tiebreak
  if (tid == 0) {
    for (int e = 0; e < ucnt; ++e) u_sel[e] = 0;
    for (int t = 0; t < m; ++t) {
      int best = -1;
      for (int e = 0; e < ucnt; ++e) {
        if (u_sel[e]) continue;
        if (best < 0 || u_val[e] > u_val[best] ||
            (u_val[e] == u_val[best] && u_idx[e] < u_idx[best])) best = e;
      }
      if (best >= 0) u_sel[best] = 1;
    }
  }
  __syncthreads();

  // --- bulk write: sure-keeps get relu(approx), everything else 0
  #pragma unroll
  for (int j = 0; j < 24; ++j) {
    float4 out;
    #pragma unroll
    for (int c = 0; c < 4; ++c) {
      const float v = key2f(key[j*4+c]);
      (&out.x)[c] = (v > thrHi) ? fmaxf(v, 0.0f) : 0.0f;
    }
    reinterpret_cast<float4*>(Crow)[tid + j*256] = out;
  }
  __syncthreads();

  // --- overwrite selected candidates with relu(exact)
  for (int e = tid; e < ucnt; e += 256)
    if (u_sel[e]) Crow[u_idx[e]] = fmaxf((float)u_val[e], 0.0f);
}

// ---------------------------------------------------------------------------
extern "C" void kernel_launch(void* const* d_in, const int* in_sizes, int n_in,
                              void* d_out, int out_size, void* d_ws, size_t ws_size,
                              hipStream_t stream) {
  const float* h        = (const float*)d_in[0];
  const float* W        = (const float*)d_in[1];
  const float* pre_bias = (const float*)d_in[2];
  const float* enc_bias = (const float*)d_in[3];
  float* C = (float*)d_out;

  const size_t a1_bytes = (size_t)N_TOKENS * D_MODEL * sizeof(_Float16);
  const size_t b1_bytes = (size_t)D_SPARSE * D_MODEL * sizeof(_Float16);
  if (ws_size < a1_bytes + b1_bytes) return;

  _Float16* A1 = (_Float16*)d_ws;
  _Float16* B1 = (_Float16*)((char*)d_ws + a1_bytes);

  convert_h_kernel<<<2048, 256, 0, stream>>>(h, pre_bias, A1);
  convert_w_kernel<<<4096, 256, 0, stream>>>(W, B1);
  gemm_kernel<<<(N_TOKENS/BM) * (D_SPARSE/BN), 256, 0, stream>>>(A1, B1, enc_bias, C);
  topk_kernel<<<N_TOKENS, 256, 0, stream>>>(C, h, pre_bias, W, enc_bias);
}

// Round 4
// 3040.643 us; speedup vs baseline: 1.2244x; 1.1464x over previous
//
#include <hip/hip_runtime.h>
#include <cstdint>
#include <cstddef>

#define D_MODEL   3072
#define D_SPARSE  24576
#define N_TOKENS  8192
#define K_SPARSE  128
#define NT        (D_MODEL/64)   // 48 K-tiles of BK=64

typedef _Float16 half8  __attribute__((ext_vector_type(8)));
typedef _Float16 half4v __attribute__((ext_vector_type(4)));
typedef float    f32x4  __attribute__((ext_vector_type(4)));

#define SCALE_A   64.0f
#define SCALE_B   4096.0f
#define INV_SCALE (1.0f/(SCALE_A*SCALE_B))   // 2^-18, exact

#define DELTA 6.0e-3f
#define MAXU  256

#define GLOBAL_AS(p) ((const __attribute__((address_space(1))) uint32_t*)(p))
#define LDS_AS(p)    ((__attribute__((address_space(3))) uint32_t*)(p))

// ---------- converts: fp32 -> fp16 (single hi limb), scaled ----------
__global__ void convert_h_kernel(const float* __restrict__ h,
                                 const float* __restrict__ pre_bias,
                                 _Float16* __restrict__ A1) {
  const int total4 = N_TOKENS * (D_MODEL/4);
  for (int m = blockIdx.x*blockDim.x + threadIdx.x; m < total4; m += gridDim.x*blockDim.x) {
    const int c4 = m % (D_MODEL/4);
    const float4 v  = reinterpret_cast<const float4*>(h)[m];
    const float4 pb = reinterpret_cast<const float4*>(pre_bias)[c4];
    half4v o;
    o[0] = (_Float16)((v.x-pb.x)*SCALE_A); o[1] = (_Float16)((v.y-pb.y)*SCALE_A);
    o[2] = (_Float16)((v.z-pb.z)*SCALE_A); o[3] = (_Float16)((v.w-pb.w)*SCALE_A);
    reinterpret_cast<half4v*>(A1)[m] = o;
  }
}

__global__ void convert_w_kernel(const float* __restrict__ W,
                                 _Float16* __restrict__ B1) {
  const int total4 = D_SPARSE * (D_MODEL/4);
  for (int m = blockIdx.x*blockDim.x + threadIdx.x; m < total4; m += gridDim.x*blockDim.x) {
    const float4 v = reinterpret_cast<const float4*>(W)[m];
    half4v o;
    o[0] = (_Float16)(v.x*SCALE_B); o[1] = (_Float16)(v.y*SCALE_B);
    o[2] = (_Float16)(v.z*SCALE_B); o[3] = (_Float16)(v.w*SCALE_B);
    reinterpret_cast<half4v*>(B1)[m] = o;
  }
}

// ---------- 256x256 8-phase GEMM: C = (A1 . B1^T)*2^-18 + enc_bias ----------
// 8 waves (2M x 4N), BK=64 split into two 32-wide k-sub-planes, LDS 128 KiB.
// T1 XCD swizzle, T2 xor-swizzle (pre-swizzled global source), T3/T4 counted
// vmcnt(8) pipeline (2 VMEM per wave per phase), T5 setprio around MFMA.
__global__ __launch_bounds__(512) void gemm_kernel(const _Float16* __restrict__ A1,
                                                   const _Float16* __restrict__ B1,
                                                   const float* __restrict__ enc_bias,
                                                   float* __restrict__ C) {
  // [buf][ksub][row 256][col 32] fp16 ; each ksub-plane contiguous 16 KiB
  __shared__ _Float16 As[2][2][256][32];   // 64 KiB
  __shared__ _Float16 Bs[2][2][256][32];   // 64 KiB

  // bijective XCD swizzle (3072 % 8 == 0), then bn-major within XCD (A-panel reuse)
  const int nwg = (N_TOKENS/256) * (D_SPARSE/256);      // 3072
  const int cpx = nwg / 8;                              // 384
  const int swz = (blockIdx.x & 7) * cpx + (blockIdx.x >> 3);
  const int bm = swz / (D_SPARSE/256);
  const int bn = swz % (D_SPARSE/256);

  const int tid  = threadIdx.x;
  const int lane = tid & 63;
  const int wid  = tid >> 6;          // 0..7
  const int wm = wid >> 2;            // 0..1 -> 128-row half
  const int wn = wid & 3;             // 0..3 -> 64-col strip

  const int r16   = lane & 15;
  const int khalf = lane >> 4;                    // 0..3 (16B slot)
  const int slot8 = ((khalf ^ (r16 & 3)) << 3);   // swizzled read slot (fp16 units)

  const _Float16* gA = A1 + (size_t)bm * 256 * D_MODEL;
  const _Float16* gB = B1 + (size_t)bn * 256 * D_MODEL;

  // staging geometry: 1024 chunks of 16B per ksub-plane; this thread's chunk = tid, tid+512
  const int c0 = tid;
  const int r0 = c0 >> 2;                          // plane row 0..127 (+128 for chunk1)
  const int s0 = (c0 & 3) ^ (r0 & 3);              // inverse-swizzled source slot
  const size_t goff0 = (size_t)r0 * D_MODEL + s0 * 8;
  const size_t goff1 = goff0 + (size_t)128 * D_MODEL;   // chunk1: row+128, same slot
  const int ldsOff0 = wid * 512;                   // fp16 units (wave covers 64 chunks)
  const int ldsOff1 = 4096 + wid * 512;

  #define STAGE(gsrc, lplane, kb) do { \
    __builtin_amdgcn_global_load_lds(GLOBAL_AS((gsrc) + goff0 + (kb)), LDS_AS((lplane) + ldsOff0), 16, 0, 0); \
    __builtin_amdgcn_global_load_lds(GLOBAL_AS((gsrc) + goff1 + (kb)), LDS_AS((lplane) + ldsOff1), 16, 0, 0); \
  } while (0)

  #define WAIT_VM8  asm volatile("s_waitcnt vmcnt(8)" ::: "memory")
  #define WAIT_LGKM asm volatile("s_waitcnt lgkmcnt(0)" ::: "memory")
  #define BAR()     __builtin_amdgcn_s_barrier()

  f32x4 acc[8][4] = {};
  half8 af[8], bf0, bf1;

  // ---- prologue: issue 6 pairs in steady-state age order ----
  STAGE(gA, &As[0][0][0][0], 0);          // A k0 (t=0)
  STAGE(gB, &Bs[0][0][0][0], 0);          // B k0 (t=0)
  STAGE(gA, &As[0][1][0][0], 32);         // A k1 (t=0)
  STAGE(gB, &Bs[0][1][0][0], 32);         // B k1 (t=0)
  STAGE(gA, &As[1][0][0][0], 64);         // A k0 (t=1)
  STAGE(gB, &Bs[1][0][0][0], 64);         // B k0 (t=1)
  WAIT_VM8; BAR();

  #pragma unroll 1
  for (int t = 0; t < NT; ++t) {
    const int buf = t & 1, nbuf = buf ^ 1;
    const int kt1 = (t+1 < NT ? t+1 : NT-1) * 64;   // clamped (redundant loads are benign)
    const int kt2 = (t+2 < NT ? t+2 : NT-1) * 64;
    const _Float16* Ap0 = &As[buf][0][0][0];
    const _Float16* Bp0 = &Bs[buf][0][0][0];
    const _Float16* Ap1 = &As[buf][1][0][0];
    const _Float16* Bp1 = &Bs[buf][1][0][0];

    // ---- phase 0: read A k0 + B k0 n01 ; stage A-k1(t+1) ----
    #pragma unroll
    for (int mi = 0; mi < 8; ++mi)
      af[mi] = *reinterpret_cast<const half8*>(Ap0 + (wm*128 + mi*16 + r16)*32 + slot8);
    bf0 = *reinterpret_cast<const half8*>(Bp0 + (wn*64 +  0 + r16)*32 + slot8);
    bf1 = *reinterpret_cast<const half8*>(Bp0 + (wn*64 + 16 + r16)*32 + slot8);
    STAGE(gA, &As[nbuf][1][0][0], kt1 + 32);
    BAR(); WAIT_LGKM;
    __builtin_amdgcn_s_setprio(1);
    #pragma unroll
    for (int mi = 0; mi < 8; ++mi) {
      acc[mi][0] = __builtin_amdgcn_mfma_f32_16x16x32_f16(af[mi], bf0, acc[mi][0], 0, 0, 0);
      acc[mi][1] = __builtin_amdgcn_mfma_f32_16x16x32_f16(af[mi], bf1, acc[mi][1], 0, 0, 0);
    }
    __builtin_amdgcn_s_setprio(0);
    BAR();

    // ---- phase 1: read B k0 n23 ; stage B-k1(t+1) ----
    bf0 = *reinterpret_cast<const half8*>(Bp0 + (wn*64 + 32 + r16)*32 + slot8);
    bf1 = *reinterpret_cast<const half8*>(Bp0 + (wn*64 + 48 + r16)*32 + slot8);
    STAGE(gB, &Bs[nbuf][1][0][0], kt1 + 32);
    BAR(); WAIT_LGKM;
    __builtin_amdgcn_s_setprio(1);
    #pragma unroll
    for (int mi = 0; mi < 8; ++mi) {
      acc[mi][2] = __builtin_amdgcn_mfma_f32_16x16x32_f16(af[mi], bf0, acc[mi][2], 0, 0, 0);
      acc[mi][3] = __builtin_amdgcn_mfma_f32_16x16x32_f16(af[mi], bf1, acc[mi][3], 0, 0, 0);
    }
    __builtin_amdgcn_s_setprio(0);
    WAIT_VM8; BAR();

    // ---- phase 2: read A k1 + B k1 n01 ; stage A-k0(t+2) ----
    #pragma unroll
    for (int mi = 0; mi < 8; ++mi)
      af[mi] = *reinterpret_cast<const half8*>(Ap1 + (wm*128 + mi*16 + r16)*32 + slot8);
    bf0 = *reinterpret_cast<const half8*>(Bp1 + (wn*64 +  0 + r16)*32 + slot8);
    bf1 = *reinterpret_cast<const half8*>(Bp1 + (wn*64 + 16 + r16)*32 + slot8);
    STAGE(gA, &As[buf][0][0][0], kt2);
    BAR(); WAIT_LGKM;
    __builtin_amdgcn_s_setprio(1);
    #pragma unroll
    for (int mi = 0; mi < 8; ++mi) {
      acc[mi][0] = __builtin_amdgcn_mfma_f32_16x16x32_f16(af[mi], bf0, acc[mi][0], 0, 0, 0);
      acc[mi][1] = __builtin_amdgcn_mfma_f32_16x16x32_f16(af[mi], bf1, acc[mi][1], 0, 0, 0);
    }
    __builtin_amdgcn_s_setprio(0);
    BAR();

    // ---- phase 3: read B k1 n23 ; stage B-k0(t+2) ----
    bf0 = *reinterpret_cast<const half8*>(Bp1 + (wn*64 + 32 + r16)*32 + slot8);
    bf1 = *reinterpret_cast<const half8*>(Bp1 + (wn*64 + 48 + r16)*32 + slot8);
    STAGE(gB, &Bs[buf][0][0][0], kt2);
    BAR(); WAIT_LGKM;
    __builtin_amdgcn_s_setprio(1);
    #pragma unroll
    for (int mi = 0; mi < 8; ++mi) {
      acc[mi][2] = __builtin_amdgcn_mfma_f32_16x16x32_f16(af[mi], bf0, acc[mi][2], 0, 0, 0);
      acc[mi][3] = __builtin_amdgcn_mfma_f32_16x16x32_f16(af[mi], bf1, acc[mi][3], 0, 0, 0);
    }
    __builtin_amdgcn_s_setprio(0);
    WAIT_VM8; BAR();
  }

  asm volatile("s_waitcnt vmcnt(0) lgkmcnt(0)" ::: "memory");

  // epilogue: C/D layout col=lane&15, row=(lane>>4)*4+reg [m89-verified]
  const int row0 = bm*256 + wm*128 + khalf*4;
  const int col0 = bn*256 + wn*64 + r16;
  #pragma unroll
  for (int ni = 0; ni < 4; ++ni) {
    const int col = col0 + ni*16;
    const float b = enc_bias[col];
    #pragma unroll
    for (int mi = 0; mi < 8; ++mi) {
      const int row = row0 + mi*16;
      #pragma unroll
      for (int r = 0; r < 4; ++r)
        C[(size_t)(row + r) * D_SPARSE + col] = acc[mi][ni][r] * INV_SCALE + b;
    }
  }
  #undef STAGE
  #undef WAIT_VM8
  #undef WAIT_LGKM
  #undef BAR
}

// ---------- top-k with exact fp64 rescue at the rank boundary ----------
__device__ __forceinline__ uint32_t f2key(float f) {
  uint32_t b = __float_as_uint(f);
  return (b & 0x80000000u) ? ~b : (b | 0x80000000u);
}
__device__ __forceinline__ float key2f(uint32_t k) {
  uint32_t b = (k & 0x80000000u) ? (k ^ 0x80000000u) : ~k;
  return __uint_as_float(b);
}

__global__ __launch_bounds__(256) void topk_kernel(float* __restrict__ C,
                                                   const float* __restrict__ h,
                                                   const float* __restrict__ pre_bias,
                                                   const float* __restrict__ W,
                                                   const float* __restrict__ enc_bias) {
  const int row = blockIdx.x;
  float* __restrict__ Crow = C + (size_t)row * D_SPARSE;
  const int tid  = threadIdx.x;
  const int lane = tid & 63;
  const int wid  = tid >> 6;

  __shared__ int hist4[4][256];
  __shared__ int wsum[4];
  __shared__ int s_found, s_digit, s_rem;
  __shared__ int s_above0, s_nabove, s_ucnt;
  __shared__ int u_idx[MAXU];
  __shared__ double u_val[MAXU];
  __shared__ unsigned char u_sel[MAXU];

  uint32_t key[96];
  #pragma unroll
  for (int j = 0; j < 24; ++j) {
    const float4 v = reinterpret_cast<const float4*>(Crow)[tid + j*256];
    key[j*4+0] = f2key(v.x); key[j*4+1] = f2key(v.y);
    key[j*4+2] = f2key(v.z); key[j*4+3] = f2key(v.w);
  }

  const uint32_t k0 = f2key(2.0f);
  int myc = 0;
  #pragma unroll
  for (int j = 0; j < 96; ++j) myc += (key[j] > k0) ? 1 : 0;
  if (tid == 0) s_above0 = 0;
  __syncthreads();
  atomicAdd(&s_above0, myc);
  __syncthreads();
  const uint32_t kmin = (s_above0 >= K_SPARSE) ? (k0 + 1u) : 0u;

  uint32_t prefix = 0, pmask = 0;
  int remaining = K_SPARSE;
  for (int level = 0; level < 4; ++level) {
    const int shift = 24 - 8*level;
    #pragma unroll
    for (int w = 0; w < 4; ++w) hist4[w][tid] = 0;
    __syncthreads();
    #pragma unroll
    for (int j = 0; j < 96; ++j) {
      const uint32_t k = key[j];
      if (k >= kmin && (k & pmask) == prefix)
        atomicAdd(&hist4[wid][(k >> shift) & 255], 1);
    }
    if (tid == 0) s_found = 1 << 30;
    __syncthreads();

    const int bin = 255 - tid;
    const int cnt = hist4[0][bin] + hist4[1][bin] + hist4[2][bin] + hist4[3][bin];
    int sc = cnt;
    #pragma unroll
    for (int d = 1; d < 64; d <<= 1) {
      const int o = __shfl_up(sc, d, 64);
      if (lane >= d) sc += o;
    }
    if (lane == 63) wsum[wid] = sc;
    __syncthreads();
    int woff = 0;
    for (int w = 0; w < wid; ++w) woff += wsum[w];
    sc += woff;
    if (sc >= remaining) atomicMin(&s_found, tid);
    __syncthreads();
    if (tid == s_found) { s_digit = bin; s_rem = remaining - (sc - cnt); }
    __syncthreads();
    prefix |= ((uint32_t)s_digit) << shift;
    pmask  |= 0xFFu << shift;
    remaining = s_rem;
    __syncthreads();
  }

  const float kth   = key2f(prefix);
  const float thrHi = kth + DELTA;
  const float thrLo = kth - DELTA;

  if (tid == 0) { s_nabove = 0; s_ucnt = 0; }
  __syncthreads();

  int myAbove = 0;
  #pragma unroll
  for (int j = 0; j < 96; ++j) {
    const float v = key2f(key[j]);
    if (v > thrHi) myAbove++;
    else if (v >= thrLo) {
      const int p = atomicAdd(&s_ucnt, 1);
      if (p < MAXU) u_idx[p] = ((tid + ((j >> 2) << 8)) << 2) + (j & 3);
    }
  }
  atomicAdd(&s_nabove, myAbove);
  __syncthreads();

  const int ucnt = s_ucnt < MAXU ? s_ucnt : MAXU;
  int m = K_SPARSE - s_nabove;
  if (m < 0) m = 0; if (m > ucnt) m = ucnt;

  const float* hrow = h + (size_t)row * D_MODEL;
  for (int e = wid; e < ucnt; e += 4) {
    const int ci = u_idx[e];
    const float* wrow = W + (size_t)ci * D_MODEL;
    double s = 0.0;
    for (int k = lane; k < D_MODEL; k += 64)
      s += (double)(hrow[k] - pre_bias[k]) * (double)wrow[k];
    #pragma unroll
    for (int off = 32; off; off >>= 1) s += __shfl_down(s, off, 64);
    if (lane == 0) u_val[e] = s + (double)enc_bias[ci];
  }
  __syncthreads();

  if (tid == 0) {
    for (int e = 0; e < ucnt; ++e) u_sel[e] = 0;
    for (int t = 0; t < m; ++t) {
      int best = -1;
      for (int e = 0; e < ucnt; ++e) {
        if (u_sel[e]) continue;
        if (best < 0 || u_val[e] > u_val[best] ||
            (u_val[e] == u_val[best] && u_idx[e] < u_idx[best])) best = e;
      }
      if (best >= 0) u_sel[best] = 1;
    }
  }
  __syncthreads();

  #pragma unroll
  for (int j = 0; j < 24; ++j) {
    float4 out;
    #pragma unroll
    for (int c = 0; c < 4; ++c) {
      const float v = key2f(key[j*4+c]);
      (&out.x)[c] = (v > thrHi) ? fmaxf(v, 0.0f) : 0.0f;
    }
    reinterpret_cast<float4*>(Crow)[tid + j*256] = out;
  }
  __syncthreads();

  for (int e = tid; e < ucnt; e += 256)
    if (u_sel[e]) Crow[u_idx[e]] = fmaxf((float)u_val[e], 0.0f);
}

// ---------------------------------------------------------------------------
extern "C" void kernel_launch(void* const* d_in, const int* in_sizes, int n_in,
                              void* d_out, int out_size, void* d_ws, size_t ws_size,
                              hipStream_t stream) {
  const float* h        = (const float*)d_in[0];
  const float* W        = (const float*)d_in[1];
  const float* pre_bias = (const float*)d_in[2];
  const float* enc_bias = (const float*)d_in[3];
  float* C = (float*)d_out;

  const size_t a1_bytes = (size_t)N_TOKENS * D_MODEL * sizeof(_Float16);
  const size_t b1_bytes = (size_t)D_SPARSE * D_MODEL * sizeof(_Float16);
  if (ws_size < a1_bytes + b1_bytes) return;

  _Float16* A1 = (_Float16*)d_ws;
  _Float16* B1 = (_Float16*)((char*)d_ws + a1_bytes);

  convert_h_kernel<<<2048, 256, 0, stream>>>(h, pre_bias, A1);
  convert_w_kernel<<<4096, 256, 0, stream>>>(W, B1);
  gemm_kernel<<<(N_TOKENS/256) * (D_SPARSE/256), 512, 0, stream>>>(A1, B1, enc_bias, C);
  topk_kernel<<<N_TOKENS, 256, 0, stream>>>(C, h, pre_bias, W, enc_bias);
}

// Round 5
// 2163.394 us; speedup vs baseline: 1.7209x; 1.4055x over previous
//
#include <hip/hip_runtime.h>
#include <cstdint>
#include <cstddef>

#define D_MODEL   3072
#define D_SPARSE  24576
#define N_TOKENS  8192
#define K_SPARSE  128
#define NT        (D_MODEL/64)   // 48 K-tiles of BK=64

typedef _Float16 half8  __attribute__((ext_vector_type(8)));
typedef _Float16 half4v __attribute__((ext_vector_type(4)));
typedef float    f32x4  __attribute__((ext_vector_type(4)));

#define SCALE_A   64.0f
#define SCALE_B   4096.0f
#define INV_SCALE (1.0f/(SCALE_A*SCALE_B))   // 2^-18, exact

#define DELTA 6.0e-3f
#define MAXU  256
#define CAP   1536      // compact-list capacity (expected ~560, 20 sigma margin)
#define GUARD 2.0f      // prefilter threshold; 128th value ~2.56 (19 sigma above)
#define SEG   4096      // topk_write span per block

#define GLOBAL_AS(p) ((const __attribute__((address_space(1))) uint32_t*)(p))
#define LDS_AS(p)    ((__attribute__((address_space(3))) uint32_t*)(p))

// ---------- converts: fp32 -> fp16 (single hi limb), scaled ----------
__global__ void convert_h_kernel(const float* __restrict__ h,
                                 const float* __restrict__ pre_bias,
                                 _Float16* __restrict__ A1) {
  const int total4 = N_TOKENS * (D_MODEL/4);
  for (int m = blockIdx.x*blockDim.x + threadIdx.x; m < total4; m += gridDim.x*blockDim.x) {
    const int c4 = m % (D_MODEL/4);
    const float4 v  = reinterpret_cast<const float4*>(h)[m];
    const float4 pb = reinterpret_cast<const float4*>(pre_bias)[c4];
    half4v o;
    o[0] = (_Float16)((v.x-pb.x)*SCALE_A); o[1] = (_Float16)((v.y-pb.y)*SCALE_A);
    o[2] = (_Float16)((v.z-pb.z)*SCALE_A); o[3] = (_Float16)((v.w-pb.w)*SCALE_A);
    reinterpret_cast<half4v*>(A1)[m] = o;
  }
}

__global__ void convert_w_kernel(const float* __restrict__ W,
                                 _Float16* __restrict__ B1) {
  const int total4 = D_SPARSE * (D_MODEL/4);
  for (int m = blockIdx.x*blockDim.x + threadIdx.x; m < total4; m += gridDim.x*blockDim.x) {
    const float4 v = reinterpret_cast<const float4*>(W)[m];
    half4v o;
    o[0] = (_Float16)(v.x*SCALE_B); o[1] = (_Float16)(v.y*SCALE_B);
    o[2] = (_Float16)(v.z*SCALE_B); o[3] = (_Float16)(v.w*SCALE_B);
    reinterpret_cast<half4v*>(B1)[m] = o;
  }
}

// ---------- 256x256 8-phase GEMM (unchanged from round 4) ----------
__global__ __launch_bounds__(512) void gemm_kernel(const _Float16* __restrict__ A1,
                                                   const _Float16* __restrict__ B1,
                                                   const float* __restrict__ enc_bias,
                                                   float* __restrict__ C) {
  __shared__ _Float16 As[2][2][256][32];   // 64 KiB
  __shared__ _Float16 Bs[2][2][256][32];   // 64 KiB

  const int nwg = (N_TOKENS/256) * (D_SPARSE/256);      // 3072
  const int cpx = nwg / 8;
  const int swz = (blockIdx.x & 7) * cpx + (blockIdx.x >> 3);
  const int bm = swz / (D_SPARSE/256);
  const int bn = swz % (D_SPARSE/256);

  const int tid  = threadIdx.x;
  const int lane = tid & 63;
  const int wid  = tid >> 6;
  const int wm = wid >> 2;
  const int wn = wid & 3;

  const int r16   = lane & 15;
  const int khalf = lane >> 4;
  const int slot8 = ((khalf ^ (r16 & 3)) << 3);

  const _Float16* gA = A1 + (size_t)bm * 256 * D_MODEL;
  const _Float16* gB = B1 + (size_t)bn * 256 * D_MODEL;

  const int c0 = tid;
  const int r0 = c0 >> 2;
  const int s0 = (c0 & 3) ^ (r0 & 3);
  const size_t goff0 = (size_t)r0 * D_MODEL + s0 * 8;
  const size_t goff1 = goff0 + (size_t)128 * D_MODEL;
  const int ldsOff0 = wid * 512;
  const int ldsOff1 = 4096 + wid * 512;

  #define STAGE(gsrc, lplane, kb) do { \
    __builtin_amdgcn_global_load_lds(GLOBAL_AS((gsrc) + goff0 + (kb)), LDS_AS((lplane) + ldsOff0), 16, 0, 0); \
    __builtin_amdgcn_global_load_lds(GLOBAL_AS((gsrc) + goff1 + (kb)), LDS_AS((lplane) + ldsOff1), 16, 0, 0); \
  } while (0)

  #define WAIT_VM8  asm volatile("s_waitcnt vmcnt(8)" ::: "memory")
  #define WAIT_LGKM asm volatile("s_waitcnt lgkmcnt(0)" ::: "memory")
  #define BAR()     __builtin_amdgcn_s_barrier()

  f32x4 acc[8][4] = {};
  half8 af[8], bf0, bf1;

  STAGE(gA, &As[0][0][0][0], 0);
  STAGE(gB, &Bs[0][0][0][0], 0);
  STAGE(gA, &As[0][1][0][0], 32);
  STAGE(gB, &Bs[0][1][0][0], 32);
  STAGE(gA, &As[1][0][0][0], 64);
  STAGE(gB, &Bs[1][0][0][0], 64);
  WAIT_VM8; BAR();

  #pragma unroll 1
  for (int t = 0; t < NT; ++t) {
    const int buf = t & 1, nbuf = buf ^ 1;
    const int kt1 = (t+1 < NT ? t+1 : NT-1) * 64;
    const int kt2 = (t+2 < NT ? t+2 : NT-1) * 64;
    const _Float16* Ap0 = &As[buf][0][0][0];
    const _Float16* Bp0 = &Bs[buf][0][0][0];
    const _Float16* Ap1 = &As[buf][1][0][0];
    const _Float16* Bp1 = &Bs[buf][1][0][0];

    #pragma unroll
    for (int mi = 0; mi < 8; ++mi)
      af[mi] = *reinterpret_cast<const half8*>(Ap0 + (wm*128 + mi*16 + r16)*32 + slot8);
    bf0 = *reinterpret_cast<const half8*>(Bp0 + (wn*64 +  0 + r16)*32 + slot8);
    bf1 = *reinterpret_cast<const half8*>(Bp0 + (wn*64 + 16 + r16)*32 + slot8);
    STAGE(gA, &As[nbuf][1][0][0], kt1 + 32);
    BAR(); WAIT_LGKM;
    __builtin_amdgcn_s_setprio(1);
    #pragma unroll
    for (int mi = 0; mi < 8; ++mi) {
      acc[mi][0] = __builtin_amdgcn_mfma_f32_16x16x32_f16(af[mi], bf0, acc[mi][0], 0, 0, 0);
      acc[mi][1] = __builtin_amdgcn_mfma_f32_16x16x32_f16(af[mi], bf1, acc[mi][1], 0, 0, 0);
    }
    __builtin_amdgcn_s_setprio(0);
    BAR();

    bf0 = *reinterpret_cast<const half8*>(Bp0 + (wn*64 + 32 + r16)*32 + slot8);
    bf1 = *reinterpret_cast<const half8*>(Bp0 + (wn*64 + 48 + r16)*32 + slot8);
    STAGE(gB, &Bs[nbuf][1][0][0], kt1 + 32);
    BAR(); WAIT_LGKM;
    __builtin_amdgcn_s_setprio(1);
    #pragma unroll
    for (int mi = 0; mi < 8; ++mi) {
      acc[mi][2] = __builtin_amdgcn_mfma_f32_16x16x32_f16(af[mi], bf0, acc[mi][2], 0, 0, 0);
      acc[mi][3] = __builtin_amdgcn_mfma_f32_16x16x32_f16(af[mi], bf1, acc[mi][3], 0, 0, 0);
    }
    __builtin_amdgcn_s_setprio(0);
    WAIT_VM8; BAR();

    #pragma unroll
    for (int mi = 0; mi < 8; ++mi)
      af[mi] = *reinterpret_cast<const half8*>(Ap1 + (wm*128 + mi*16 + r16)*32 + slot8);
    bf0 = *reinterpret_cast<const half8*>(Bp1 + (wn*64 +  0 + r16)*32 + slot8);
    bf1 = *reinterpret_cast<const half8*>(Bp1 + (wn*64 + 16 + r16)*32 + slot8);
    STAGE(gA, &As[buf][0][0][0], kt2);
    BAR(); WAIT_LGKM;
    __builtin_amdgcn_s_setprio(1);
    #pragma unroll
    for (int mi = 0; mi < 8; ++mi) {
      acc[mi][0] = __builtin_amdgcn_mfma_f32_16x16x32_f16(af[mi], bf0, acc[mi][0], 0, 0, 0);
      acc[mi][1] = __builtin_amdgcn_mfma_f32_16x16x32_f16(af[mi], bf1, acc[mi][1], 0, 0, 0);
    }
    __builtin_amdgcn_s_setprio(0);
    BAR();

    bf0 = *reinterpret_cast<const half8*>(Bp1 + (wn*64 + 32 + r16)*32 + slot8);
    bf1 = *reinterpret_cast<const half8*>(Bp1 + (wn*64 + 48 + r16)*32 + slot8);
    STAGE(gB, &Bs[buf][0][0][0], kt2);
    BAR(); WAIT_LGKM;
    __builtin_amdgcn_s_setprio(1);
    #pragma unroll
    for (int mi = 0; mi < 8; ++mi) {
      acc[mi][2] = __builtin_amdgcn_mfma_f32_16x16x32_f16(af[mi], bf0, acc[mi][2], 0, 0, 0);
      acc[mi][3] = __builtin_amdgcn_mfma_f32_16x16x32_f16(af[mi], bf1, acc[mi][3], 0, 0, 0);
    }
    __builtin_amdgcn_s_setprio(0);
    WAIT_VM8; BAR();
  }

  asm volatile("s_waitcnt vmcnt(0) lgkmcnt(0)" ::: "memory");

  const int row0 = bm*256 + wm*128 + khalf*4;
  const int col0 = bn*256 + wn*64 + r16;
  #pragma unroll
  for (int ni = 0; ni < 4; ++ni) {
    const int col = col0 + ni*16;
    const float b = enc_bias[col];
    #pragma unroll
    for (int mi = 0; mi < 8; ++mi) {
      const int row = row0 + mi*16;
      #pragma unroll
      for (int r = 0; r < 4; ++r)
        C[(size_t)(row + r) * D_SPARSE + col] = acc[mi][ni][r] * INV_SCALE + b;
    }
  }
  #undef STAGE
  #undef WAIT_VM8
  #undef WAIT_LGKM
  #undef BAR
}

// ---------- top-k select: compact >GUARD, exact radix on list, fp64 rescue ----------
__device__ __forceinline__ uint32_t f2key(float f) {
  uint32_t b = __float_as_uint(f);
  return (b & 0x80000000u) ? ~b : (b | 0x80000000u);
}
__device__ __forceinline__ float key2f(uint32_t k) {
  uint32_t b = (k & 0x80000000u) ? (k ^ 0x80000000u) : ~k;
  return __uint_as_float(b);
}

__global__ __launch_bounds__(256) void topk_select(const float* __restrict__ C,
                                                   const float* __restrict__ h,
                                                   const float* __restrict__ pre_bias,
                                                   const float* __restrict__ W,
                                                   const float* __restrict__ enc_bias,
                                                   int2* __restrict__ lists) {
  const int row = blockIdx.x;
  const float* __restrict__ Crow = C + (size_t)row * D_SPARSE;
  const int tid  = threadIdx.x;
  const int lane = tid & 63;
  const int wid  = tid >> 6;

  __shared__ float lv[CAP];
  __shared__ int   li[CAP];
  __shared__ int hist4[4][256];
  __shared__ int wsum[4];
  __shared__ int s_cnt, s_found, s_digit, s_rem, s_ucnt, s_emit;
  __shared__ int u_idx[MAXU];
  __shared__ double u_val[MAXU];
  __shared__ unsigned char u_sel[MAXU];

  if (tid == 0) s_cnt = 0;
  __syncthreads();

  // ---- pass 1: stream row, compact values > GUARD into LDS list ----
  for (int j = 0; j < 24; ++j) {
    const float4 v = reinterpret_cast<const float4*>(Crow)[tid + j*256];
    const int base = (tid + j*256) * 4;
    #pragma unroll
    for (int c = 0; c < 4; ++c) {
      const float x = (&v.x)[c];
      if (x > GUARD) {
        const int p = atomicAdd(&s_cnt, 1);
        if (p < CAP) { lv[p] = x; li[p] = base + c; }
      }
    }
  }
  __syncthreads();
  const int cnt = s_cnt;
  bool mainok = (cnt >= K_SPARSE && cnt <= CAP);
  float kth = 0.0f;

  if (mainok) {
    // exact 4-level radix on the compact list (positive fp32: raw bits monotone)
    uint32_t prefix = 0, pmask = 0;
    int remaining = K_SPARSE;
    for (int level = 0; level < 4; ++level) {
      const int shift = 24 - 8*level;
      #pragma unroll
      for (int w = 0; w < 4; ++w) hist4[w][tid] = 0;
      if (tid == 0) s_found = 1 << 30;
      __syncthreads();
      for (int e = tid; e < cnt; e += 256) {
        const uint32_t k = __float_as_uint(lv[e]);
        if ((k & pmask) == prefix) atomicAdd(&hist4[wid][(k >> shift) & 255], 1);
      }
      __syncthreads();
      const int bin = 255 - tid;
      const int cb = hist4[0][bin] + hist4[1][bin] + hist4[2][bin] + hist4[3][bin];
      int sc = cb;
      #pragma unroll
      for (int d = 1; d < 64; d <<= 1) {
        const int o = __shfl_up(sc, d, 64);
        if (lane >= d) sc += o;
      }
      if (lane == 63) wsum[wid] = sc;
      __syncthreads();
      int woff = 0;
      for (int w = 0; w < wid; ++w) woff += wsum[w];
      sc += woff;
      if (sc >= remaining) atomicMin(&s_found, tid);
      __syncthreads();
      if (tid == s_found) { s_digit = bin; s_rem = remaining - (sc - cb); }
      __syncthreads();
      prefix |= ((uint32_t)s_digit) << shift;
      pmask  |= 0xFFu << shift;
      remaining = s_rem;
      __syncthreads();
    }
    kth = __uint_as_float(prefix);
    if (!(kth - DELTA > GUARD)) mainok = false;   // window must stay inside list coverage
  }

  if (!mainok) {
    // ---- fully general fallback: radix over the whole row, re-read per level ----
    uint32_t prefix = 0, pmask = 0;
    int remaining = K_SPARSE;
    for (int level = 0; level < 4; ++level) {
      const int shift = 24 - 8*level;
      #pragma unroll
      for (int w = 0; w < 4; ++w) hist4[w][tid] = 0;
      if (tid == 0) s_found = 1 << 30;
      __syncthreads();
      for (int j = 0; j < 24; ++j) {
        const float4 v = reinterpret_cast<const float4*>(Crow)[tid + j*256];
        #pragma unroll
        for (int c = 0; c < 4; ++c) {
          const uint32_t k = f2key((&v.x)[c]);
          if ((k & pmask) == prefix) atomicAdd(&hist4[wid][(k >> shift) & 255], 1);
        }
      }
      __syncthreads();
      const int bin = 255 - tid;
      const int cb = hist4[0][bin] + hist4[1][bin] + hist4[2][bin] + hist4[3][bin];
      int sc = cb;
      #pragma unroll
      for (int d = 1; d < 64; d <<= 1) {
        const int o = __shfl_up(sc, d, 64);
        if (lane >= d) sc += o;
      }
      if (lane == 63) wsum[wid] = sc;
      __syncthreads();
      int woff = 0;
      for (int w = 0; w < wid; ++w) woff += wsum[w];
      sc += woff;
      if (sc >= remaining) atomicMin(&s_found, tid);
      __syncthreads();
      if (tid == s_found) { s_digit = bin; s_rem = remaining - (sc - cb); }
      __syncthreads();
      prefix |= ((uint32_t)s_digit) << shift;
      pmask  |= 0xFFu << shift;
      remaining = s_rem;
      __syncthreads();
    }
    kth = key2f(prefix);
  }

  const float thrHi = kth + DELTA;
  const float thrLo = kth - DELTA;
  int2* __restrict__ rowlist = lists + (size_t)row * K_SPARSE;

  if (tid == 0) { s_ucnt = 0; s_emit = 0; }
  __syncthreads();

  // ---- classify: emit sure-keeps now, collect window candidates ----
  if (mainok) {
    for (int e = tid; e < cnt; e += 256) {
      const float x = lv[e];
      if (x > thrHi) {
        const int p = atomicAdd(&s_emit, 1);
        if (p < K_SPARSE) rowlist[p] = make_int2(li[e], __float_as_int(fmaxf(x, 0.0f)));
      } else if (x >= thrLo) {
        const int p = atomicAdd(&s_ucnt, 1);
        if (p < MAXU) u_idx[p] = li[e];
      }
    }
  } else {
    for (int j = 0; j < 24; ++j) {
      const float4 v = reinterpret_cast<const float4*>(Crow)[tid + j*256];
      const int base = (tid + j*256) * 4;
      #pragma unroll
      for (int c = 0; c < 4; ++c) {
        const float x = (&v.x)[c];
        if (x > thrHi) {
          const int p = atomicAdd(&s_emit, 1);
          if (p < K_SPARSE) rowlist[p] = make_int2(base + c, __float_as_int(fmaxf(x, 0.0f)));
        } else if (x >= thrLo) {
          const int p = atomicAdd(&s_ucnt, 1);
          if (p < MAXU) u_idx[p] = base + c;
        }
      }
    }
  }
  __syncthreads();

  const int nabove = s_emit;
  const int ucnt = s_ucnt < MAXU ? s_ucnt : MAXU;
  int m = K_SPARSE - nabove;
  if (m < 0) m = 0; if (m > ucnt) m = ucnt;

  // ---- exact fp64 dots for window candidates, one wave each ----
  const float* hrow = h + (size_t)row * D_MODEL;
  for (int e = wid; e < ucnt; e += 4) {
    const int ci = u_idx[e];
    const float* wrow = W + (size_t)ci * D_MODEL;
    double s = 0.0;
    for (int k = lane; k < D_MODEL; k += 64)
      s += (double)(hrow[k] - pre_bias[k]) * (double)wrow[k];
    #pragma unroll
    for (int off = 32; off; off >>= 1) s += __shfl_down(s, off, 64);
    if (lane == 0) u_val[e] = s + (double)enc_bias[ci];
  }
  __syncthreads();

  // ---- pick top-m by (exact desc, index asc) — jax tiebreak ----
  if (tid == 0) {
    for (int e = 0; e < ucnt; ++e) u_sel[e] = 0;
    for (int t = 0; t < m; ++t) {
      int best = -1;
      for (int e = 0; e < ucnt; ++e) {
        if (u_sel[e]) continue;
        if (best < 0 || u_val[e] > u_val[best] ||
            (u_val[e] == u_val[best] && u_idx[e] < u_idx[best])) best = e;
      }
      if (best >= 0) u_sel[best] = 1;
    }
  }
  __syncthreads();

  for (int e = tid; e < ucnt; e += 256)
    if (u_sel[e]) {
      const int p = atomicAdd(&s_emit, 1);
      if (p < K_SPARSE) rowlist[p] = make_int2(u_idx[e], __float_as_int(fmaxf((float)u_val[e], 0.0f)));
    }
  __syncthreads();
  if (tid == 0)
    for (int p = s_emit; p < K_SPARSE; ++p) rowlist[p] = make_int2(-1, 0);  // pad (never taken)
}

// ---------- top-k write: zero + scatter via LDS span, pure streaming ----------
__global__ __launch_bounds__(256) void topk_write(const int2* __restrict__ lists,
                                                  float* __restrict__ C) {
  const int nseg = D_SPARSE / SEG;              // 6
  const int row = blockIdx.x / nseg;
  const int seg = blockIdx.x % nseg;
  const int lo  = seg * SEG;
  const int tid = threadIdx.x;

  __shared__ float span[SEG];
  const float4 z = {0.0f, 0.0f, 0.0f, 0.0f};
  #pragma unroll
  for (int i = 0; i < SEG/1024; ++i)
    reinterpret_cast<float4*>(span)[tid + i*256] = z;
  __syncthreads();

  if (tid < K_SPARSE) {
    const int2 p = lists[(size_t)row * K_SPARSE + tid];
    const int off = p.x - lo;
    if (off >= 0 && off < SEG) span[off] = __int_as_float(p.y);
  }
  __syncthreads();

  float4* __restrict__ out4 = reinterpret_cast<float4*>(C + (size_t)row * D_SPARSE + lo);
  #pragma unroll
  for (int i = 0; i < SEG/1024; ++i)
    out4[tid + i*256] = reinterpret_cast<const float4*>(span)[tid + i*256];
}

// ---------------------------------------------------------------------------
extern "C" void kernel_launch(void* const* d_in, const int* in_sizes, int n_in,
                              void* d_out, int out_size, void* d_ws, size_t ws_size,
                              hipStream_t stream) {
  const float* h        = (const float*)d_in[0];
  const float* W        = (const float*)d_in[1];
  const float* pre_bias = (const float*)d_in[2];
  const float* enc_bias = (const float*)d_in[3];
  float* C = (float*)d_out;

  const size_t a1_bytes = (size_t)N_TOKENS * D_MODEL * sizeof(_Float16);   // 50.3 MB
  const size_t b1_bytes = (size_t)D_SPARSE * D_MODEL * sizeof(_Float16);   // 151.0 MB
  if (ws_size < a1_bytes + b1_bytes) return;

  _Float16* A1 = (_Float16*)d_ws;
  _Float16* B1 = (_Float16*)((char*)d_ws + a1_bytes);
  // lists parked in A1's region: A1 is dead after gemm_kernel, rewritten each call.
  int2* lists = (int2*)d_ws;                    // 8192*128*8B = 8 MB << a1_bytes

  convert_h_kernel<<<2048, 256, 0, stream>>>(h, pre_bias, A1);
  convert_w_kernel<<<4096, 256, 0, stream>>>(W, B1);
  gemm_kernel<<<(N_TOKENS/256) * (D_SPARSE/256), 512, 0, stream>>>(A1, B1, enc_bias, C);
  topk_select<<<N_TOKENS, 256, 0, stream>>>(C, h, pre_bias, W, enc_bias, lists);
  topk_write<<<N_TOKENS * (D_SPARSE/SEG), 256, 0, stream>>>(lists, C);
}

// Round 6
// 2105.638 us; speedup vs baseline: 1.7681x; 1.0274x over previous
//
#include <hip/hip_runtime.h>
#include <cstdint>
#include <cstddef>

#define D_MODEL   3072
#define D_SPARSE  24576
#define N_TOKENS  8192
#define K_SPARSE  128
#define NT        (D_MODEL/64)   // 48 K-tiles of BK=64

typedef _Float16 half8  __attribute__((ext_vector_type(8)));
typedef _Float16 half4v __attribute__((ext_vector_type(4)));
typedef float    f32x4  __attribute__((ext_vector_type(4)));

#define SCALE_A   64.0f
#define SCALE_B   4096.0f
#define INV_SCALE (1.0f/(SCALE_A*SCALE_B))   // 2^-18, exact

#define DELTA 6.0e-3f
#define MAXU  256
#define CAP   1536      // compact-list capacity (expected ~560, 20 sigma margin)
#define GUARD 2.0f      // prefilter threshold; 128th value ~2.56 (19 sigma above)
#define SEG   4096      // topk_write span per block

#define GLOBAL_AS(p) ((const __attribute__((address_space(1))) uint32_t*)(p))
#define LDS_AS(p)    ((__attribute__((address_space(3))) uint32_t*)(p))

// ---------- converts: fp32 -> fp16 (single hi limb), scaled ----------
__global__ void convert_h_kernel(const float* __restrict__ h,
                                 const float* __restrict__ pre_bias,
                                 _Float16* __restrict__ A1) {
  const int total4 = N_TOKENS * (D_MODEL/4);
  for (int m = blockIdx.x*blockDim.x + threadIdx.x; m < total4; m += gridDim.x*blockDim.x) {
    const int c4 = m % (D_MODEL/4);
    const float4 v  = reinterpret_cast<const float4*>(h)[m];
    const float4 pb = reinterpret_cast<const float4*>(pre_bias)[c4];
    half4v o;
    o[0] = (_Float16)((v.x-pb.x)*SCALE_A); o[1] = (_Float16)((v.y-pb.y)*SCALE_A);
    o[2] = (_Float16)((v.z-pb.z)*SCALE_A); o[3] = (_Float16)((v.w-pb.w)*SCALE_A);
    reinterpret_cast<half4v*>(A1)[m] = o;
  }
}

__global__ void convert_w_kernel(const float* __restrict__ W,
                                 _Float16* __restrict__ B1) {
  const int total4 = D_SPARSE * (D_MODEL/4);
  for (int m = blockIdx.x*blockDim.x + threadIdx.x; m < total4; m += gridDim.x*blockDim.x) {
    const float4 v = reinterpret_cast<const float4*>(W)[m];
    half4v o;
    o[0] = (_Float16)(v.x*SCALE_B); o[1] = (_Float16)(v.y*SCALE_B);
    o[2] = (_Float16)(v.z*SCALE_B); o[3] = (_Float16)(v.w*SCALE_B);
    reinterpret_cast<half4v*>(B1)[m] = o;
  }
}

// ---------- 256x256 8-phase GEMM ----------
// Identical to round 5 except the T2 swizzle exponent: p(row) = (row>>1)&3
// (was row&3, which collapses even rows onto 2 of 4 slots -> 8-way conflicts).
__global__ __launch_bounds__(512) void gemm_kernel(const _Float16* __restrict__ A1,
                                                   const _Float16* __restrict__ B1,
                                                   const float* __restrict__ enc_bias,
                                                   float* __restrict__ C) {
  __shared__ _Float16 As[2][2][256][32];   // 64 KiB
  __shared__ _Float16 Bs[2][2][256][32];   // 64 KiB

  const int nwg = (N_TOKENS/256) * (D_SPARSE/256);      // 3072
  const int cpx = nwg / 8;
  const int swz = (blockIdx.x & 7) * cpx + (blockIdx.x >> 3);
  const int bm = swz / (D_SPARSE/256);
  const int bn = swz % (D_SPARSE/256);

  const int tid  = threadIdx.x;
  const int lane = tid & 63;
  const int wid  = tid >> 6;
  const int wm = wid >> 2;
  const int wn = wid & 3;

  const int r16   = lane & 15;
  const int khalf = lane >> 4;
  const int slot8 = ((khalf ^ ((r16 >> 1) & 3)) << 3);   // FIXED: p(r)=(r>>1)&3

  const _Float16* gA = A1 + (size_t)bm * 256 * D_MODEL;
  const _Float16* gB = B1 + (size_t)bn * 256 * D_MODEL;

  const int c0 = tid;
  const int r0 = c0 >> 2;
  const int s0 = (c0 & 3) ^ ((r0 >> 1) & 3);             // FIXED: inverse of same p
  const size_t goff0 = (size_t)r0 * D_MODEL + s0 * 8;
  const size_t goff1 = goff0 + (size_t)128 * D_MODEL;
  const int ldsOff0 = wid * 512;
  const int ldsOff1 = 4096 + wid * 512;

  #define STAGE(gsrc, lplane, kb) do { \
    __builtin_amdgcn_global_load_lds(GLOBAL_AS((gsrc) + goff0 + (kb)), LDS_AS((lplane) + ldsOff0), 16, 0, 0); \
    __builtin_amdgcn_global_load_lds(GLOBAL_AS((gsrc) + goff1 + (kb)), LDS_AS((lplane) + ldsOff1), 16, 0, 0); \
  } while (0)

  #define WAIT_VM8  asm volatile("s_waitcnt vmcnt(8)" ::: "memory")
  #define WAIT_LGKM asm volatile("s_waitcnt lgkmcnt(0)" ::: "memory")
  #define BAR()     __builtin_amdgcn_s_barrier()

  f32x4 acc[8][4] = {};
  half8 af[8], bf0, bf1;

  STAGE(gA, &As[0][0][0][0], 0);
  STAGE(gB, &Bs[0][0][0][0], 0);
  STAGE(gA, &As[0][1][0][0], 32);
  STAGE(gB, &Bs[0][1][0][0], 32);
  STAGE(gA, &As[1][0][0][0], 64);
  STAGE(gB, &Bs[1][0][0][0], 64);
  WAIT_VM8; BAR();

  #pragma unroll 1
  for (int t = 0; t < NT; ++t) {
    const int buf = t & 1, nbuf = buf ^ 1;
    const int kt1 = (t+1 < NT ? t+1 : NT-1) * 64;
    const int kt2 = (t+2 < NT ? t+2 : NT-1) * 64;
    const _Float16* Ap0 = &As[buf][0][0][0];
    const _Float16* Bp0 = &Bs[buf][0][0][0];
    const _Float16* Ap1 = &As[buf][1][0][0];
    const _Float16* Bp1 = &Bs[buf][1][0][0];

    #pragma unroll
    for (int mi = 0; mi < 8; ++mi)
      af[mi] = *reinterpret_cast<const half8*>(Ap0 + (wm*128 + mi*16 + r16)*32 + slot8);
    bf0 = *reinterpret_cast<const half8*>(Bp0 + (wn*64 +  0 + r16)*32 + slot8);
    bf1 = *reinterpret_cast<const half8*>(Bp0 + (wn*64 + 16 + r16)*32 + slot8);
    STAGE(gA, &As[nbuf][1][0][0], kt1 + 32);
    BAR(); WAIT_LGKM;
    __builtin_amdgcn_s_setprio(1);
    #pragma unroll
    for (int mi = 0; mi < 8; ++mi) {
      acc[mi][0] = __builtin_amdgcn_mfma_f32_16x16x32_f16(af[mi], bf0, acc[mi][0], 0, 0, 0);
      acc[mi][1] = __builtin_amdgcn_mfma_f32_16x16x32_f16(af[mi], bf1, acc[mi][1], 0, 0, 0);
    }
    __builtin_amdgcn_s_setprio(0);
    BAR();

    bf0 = *reinterpret_cast<const half8*>(Bp0 + (wn*64 + 32 + r16)*32 + slot8);
    bf1 = *reinterpret_cast<const half8*>(Bp0 + (wn*64 + 48 + r16)*32 + slot8);
    STAGE(gB, &Bs[nbuf][1][0][0], kt1 + 32);
    BAR(); WAIT_LGKM;
    __builtin_amdgcn_s_setprio(1);
    #pragma unroll
    for (int mi = 0; mi < 8; ++mi) {
      acc[mi][2] = __builtin_amdgcn_mfma_f32_16x16x32_f16(af[mi], bf0, acc[mi][2], 0, 0, 0);
      acc[mi][3] = __builtin_amdgcn_mfma_f32_16x16x32_f16(af[mi], bf1, acc[mi][3], 0, 0, 0);
    }
    __builtin_amdgcn_s_setprio(0);
    WAIT_VM8; BAR();

    #pragma unroll
    for (int mi = 0; mi < 8; ++mi)
      af[mi] = *reinterpret_cast<const half8*>(Ap1 + (wm*128 + mi*16 + r16)*32 + slot8);
    bf0 = *reinterpret_cast<const half8*>(Bp1 + (wn*64 +  0 + r16)*32 + slot8);
    bf1 = *reinterpret_cast<const half8*>(Bp1 + (wn*64 + 16 + r16)*32 + slot8);
    STAGE(gA, &As[buf][0][0][0], kt2);
    BAR(); WAIT_LGKM;
    __builtin_amdgcn_s_setprio(1);
    #pragma unroll
    for (int mi = 0; mi < 8; ++mi) {
      acc[mi][0] = __builtin_amdgcn_mfma_f32_16x16x32_f16(af[mi], bf0, acc[mi][0], 0, 0, 0);
      acc[mi][1] = __builtin_amdgcn_mfma_f32_16x16x32_f16(af[mi], bf1, acc[mi][1], 0, 0, 0);
    }
    __builtin_amdgcn_s_setprio(0);
    BAR();

    bf0 = *reinterpret_cast<const half8*>(Bp1 + (wn*64 + 32 + r16)*32 + slot8);
    bf1 = *reinterpret_cast<const half8*>(Bp1 + (wn*64 + 48 + r16)*32 + slot8);
    STAGE(gB, &Bs[buf][0][0][0], kt2);
    BAR(); WAIT_LGKM;
    __builtin_amdgcn_s_setprio(1);
    #pragma unroll
    for (int mi = 0; mi < 8; ++mi) {
      acc[mi][2] = __builtin_amdgcn_mfma_f32_16x16x32_f16(af[mi], bf0, acc[mi][2], 0, 0, 0);
      acc[mi][3] = __builtin_amdgcn_mfma_f32_16x16x32_f16(af[mi], bf1, acc[mi][3], 0, 0, 0);
    }
    __builtin_amdgcn_s_setprio(0);
    WAIT_VM8; BAR();
  }

  asm volatile("s_waitcnt vmcnt(0) lgkmcnt(0)" ::: "memory");

  const int row0 = bm*256 + wm*128 + khalf*4;
  const int col0 = bn*256 + wn*64 + r16;
  #pragma unroll
  for (int ni = 0; ni < 4; ++ni) {
    const int col = col0 + ni*16;
    const float b = enc_bias[col];
    #pragma unroll
    for (int mi = 0; mi < 8; ++mi) {
      const int row = row0 + mi*16;
      #pragma unroll
      for (int r = 0; r < 4; ++r)
        C[(size_t)(row + r) * D_SPARSE + col] = acc[mi][ni][r] * INV_SCALE + b;
    }
  }
  #undef STAGE
  #undef WAIT_VM8
  #undef WAIT_LGKM
  #undef BAR
}

// ---------- top-k select: compact >GUARD, exact radix on list, fp64 rescue ----------
__device__ __forceinline__ uint32_t f2key(float f) {
  uint32_t b = __float_as_uint(f);
  return (b & 0x80000000u) ? ~b : (b | 0x80000000u);
}
__device__ __forceinline__ float key2f(uint32_t k) {
  uint32_t b = (k & 0x80000000u) ? (k ^ 0x80000000u) : ~k;
  return __uint_as_float(b);
}

__global__ __launch_bounds__(256) void topk_select(const float* __restrict__ C,
                                                   const float* __restrict__ h,
                                                   const float* __restrict__ pre_bias,
                                                   const float* __restrict__ W,
                                                   const float* __restrict__ enc_bias,
                                                   int2* __restrict__ lists) {
  const int row = blockIdx.x;
  const float* __restrict__ Crow = C + (size_t)row * D_SPARSE;
  const int tid  = threadIdx.x;
  const int lane = tid & 63;
  const int wid  = tid >> 6;

  __shared__ float lv[CAP];
  __shared__ int   li[CAP];
  __shared__ int hist4[4][256];
  __shared__ int wsum[4];
  __shared__ int s_cnt, s_found, s_digit, s_rem, s_ucnt, s_emit;
  __shared__ int u_idx[MAXU];
  __shared__ double u_val[MAXU];
  __shared__ unsigned char u_sel[MAXU];

  if (tid == 0) s_cnt = 0;
  __syncthreads();

  for (int j = 0; j < 24; ++j) {
    const float4 v = reinterpret_cast<const float4*>(Crow)[tid + j*256];
    const int base = (tid + j*256) * 4;
    #pragma unroll
    for (int c = 0; c < 4; ++c) {
      const float x = (&v.x)[c];
      if (x > GUARD) {
        const int p = atomicAdd(&s_cnt, 1);
        if (p < CAP) { lv[p] = x; li[p] = base + c; }
      }
    }
  }
  __syncthreads();
  const int cnt = s_cnt;
  bool mainok = (cnt >= K_SPARSE && cnt <= CAP);
  float kth = 0.0f;

  if (mainok) {
    uint32_t prefix = 0, pmask = 0;
    int remaining = K_SPARSE;
    for (int level = 0; level < 4; ++level) {
      const int shift = 24 - 8*level;
      #pragma unroll
      for (int w = 0; w < 4; ++w) hist4[w][tid] = 0;
      if (tid == 0) s_found = 1 << 30;
      __syncthreads();
      for (int e = tid; e < cnt; e += 256) {
        const uint32_t k = __float_as_uint(lv[e]);
        if ((k & pmask) == prefix) atomicAdd(&hist4[wid][(k >> shift) & 255], 1);
      }
      __syncthreads();
      const int bin = 255 - tid;
      const int cb = hist4[0][bin] + hist4[1][bin] + hist4[2][bin] + hist4[3][bin];
      int sc = cb;
      #pragma unroll
      for (int d = 1; d < 64; d <<= 1) {
        const int o = __shfl_up(sc, d, 64);
        if (lane >= d) sc += o;
      }
      if (lane == 63) wsum[wid] = sc;
      __syncthreads();
      int woff = 0;
      for (int w = 0; w < wid; ++w) woff += wsum[w];
      sc += woff;
      if (sc >= remaining) atomicMin(&s_found, tid);
      __syncthreads();
      if (tid == s_found) { s_digit = bin; s_rem = remaining - (sc - cb); }
      __syncthreads();
      prefix |= ((uint32_t)s_digit) << shift;
      pmask  |= 0xFFu << shift;
      remaining = s_rem;
      __syncthreads();
    }
    kth = __uint_as_float(prefix);
    if (!(kth - DELTA > GUARD)) mainok = false;
  }

  if (!mainok) {
    uint32_t prefix = 0, pmask = 0;
    int remaining = K_SPARSE;
    for (int level = 0; level < 4; ++level) {
      const int shift = 24 - 8*level;
      #pragma unroll
      for (int w = 0; w < 4; ++w) hist4[w][tid] = 0;
      if (tid == 0) s_found = 1 << 30;
      __syncthreads();
      for (int j = 0; j < 24; ++j) {
        const float4 v = reinterpret_cast<const float4*>(Crow)[tid + j*256];
        #pragma unroll
        for (int c = 0; c < 4; ++c) {
          const uint32_t k = f2key((&v.x)[c]);
          if ((k & pmask) == prefix) atomicAdd(&hist4[wid][(k >> shift) & 255], 1);
        }
      }
      __syncthreads();
      const int bin = 255 - tid;
      const int cb = hist4[0][bin] + hist4[1][bin] + hist4[2][bin] + hist4[3][bin];
      int sc = cb;
      #pragma unroll
      for (int d = 1; d < 64; d <<= 1) {
        const int o = __shfl_up(sc, d, 64);
        if (lane >= d) sc += o;
      }
      if (lane == 63) wsum[wid] = sc;
      __syncthreads();
      int woff = 0;
      for (int w = 0; w < wid; ++w) woff += wsum[w];
      sc += woff;
      if (sc >= remaining) atomicMin(&s_found, tid);
      __syncthreads();
      if (tid == s_found) { s_digit = bin; s_rem = remaining - (sc - cb); }
      __syncthreads();
      prefix |= ((uint32_t)s_digit) << shift;
      pmask  |= 0xFFu << shift;
      remaining = s_rem;
      __syncthreads();
    }
    kth = key2f(prefix);
  }

  const float thrHi = kth + DELTA;
  const float thrLo = kth - DELTA;
  int2* __restrict__ rowlist = lists + (size_t)row * K_SPARSE;

  if (tid == 0) { s_ucnt = 0; s_emit = 0; }
  __syncthreads();

  if (mainok) {
    for (int e = tid; e < cnt; e += 256) {
      const float x = lv[e];
      if (x > thrHi) {
        const int p = atomicAdd(&s_emit, 1);
        if (p < K_SPARSE) rowlist[p] = make_int2(li[e], __float_as_int(fmaxf(x, 0.0f)));
      } else if (x >= thrLo) {
        const int p = atomicAdd(&s_ucnt, 1);
        if (p < MAXU) u_idx[p] = li[e];
      }
    }
  } else {
    for (int j = 0; j < 24; ++j) {
      const float4 v = reinterpret_cast<const float4*>(Crow)[tid + j*256];
      const int base = (tid + j*256) * 4;
      #pragma unroll
      for (int c = 0; c < 4; ++c) {
        const float x = (&v.x)[c];
        if (x > thrHi) {
          const int p = atomicAdd(&s_emit, 1);
          if (p < K_SPARSE) rowlist[p] = make_int2(base + c, __float_as_int(fmaxf(x, 0.0f)));
        } else if (x >= thrLo) {
          const int p = atomicAdd(&s_ucnt, 1);
          if (p < MAXU) u_idx[p] = base + c;
        }
      }
    }
  }
  __syncthreads();

  const int nabove = s_emit;
  const int ucnt = s_ucnt < MAXU ? s_ucnt : MAXU;
  int m = K_SPARSE - nabove;
  if (m < 0) m = 0; if (m > ucnt) m = ucnt;

  const float* hrow = h + (size_t)row * D_MODEL;
  for (int e = wid; e < ucnt; e += 4) {
    const int ci = u_idx[e];
    const float* wrow = W + (size_t)ci * D_MODEL;
    double s = 0.0;
    for (int k = lane; k < D_MODEL; k += 64)
      s += (double)(hrow[k] - pre_bias[k]) * (double)wrow[k];
    #pragma unroll
    for (int off = 32; off; off >>= 1) s += __shfl_down(s, off, 64);
    if (lane == 0) u_val[e] = s + (double)enc_bias[ci];
  }
  __syncthreads();

  if (tid == 0) {
    for (int e = 0; e < ucnt; ++e) u_sel[e] = 0;
    for (int t = 0; t < m; ++t) {
      int best = -1;
      for (int e = 0; e < ucnt; ++e) {
        if (u_sel[e]) continue;
        if (best < 0 || u_val[e] > u_val[best] ||
            (u_val[e] == u_val[best] && u_idx[e] < u_idx[best])) best = e;
      }
      if (best >= 0) u_sel[best] = 1;
    }
  }
  __syncthreads();

  for (int e = tid; e < ucnt; e += 256)
    if (u_sel[e]) {
      const int p = atomicAdd(&s_emit, 1);
      if (p < K_SPARSE) rowlist[p] = make_int2(u_idx[e], __float_as_int(fmaxf((float)u_val[e], 0.0f)));
    }
  __syncthreads();
  if (tid == 0)
    for (int p = s_emit; p < K_SPARSE; ++p) rowlist[p] = make_int2(-1, 0);
}

// ---------- top-k write: zero + scatter via LDS span, pure streaming ----------
__global__ __launch_bounds__(256) void topk_write(const int2* __restrict__ lists,
                                                  float* __restrict__ C) {
  const int nseg = D_SPARSE / SEG;              // 6
  const int row = blockIdx.x / nseg;
  const int seg = blockIdx.x % nseg;
  const int lo  = seg * SEG;
  const int tid = threadIdx.x;

  __shared__ float span[SEG];
  const float4 z = {0.0f, 0.0f, 0.0f, 0.0f};
  #pragma unroll
  for (int i = 0; i < SEG/1024; ++i)
    reinterpret_cast<float4*>(span)[tid + i*256] = z;
  __syncthreads();

  if (tid < K_SPARSE) {
    const int2 p = lists[(size_t)row * K_SPARSE + tid];
    const int off = p.x - lo;
    if (off >= 0 && off < SEG) span[off] = __int_as_float(p.y);
  }
  __syncthreads();

  float4* __restrict__ out4 = reinterpret_cast<float4*>(C + (size_t)row * D_SPARSE + lo);
  #pragma unroll
  for (int i = 0; i < SEG/1024; ++i)
    out4[tid + i*256] = reinterpret_cast<const float4*>(span)[tid + i*256];
}

// ---------------------------------------------------------------------------
extern "C" void kernel_launch(void* const* d_in, const int* in_sizes, int n_in,
                              void* d_out, int out_size, void* d_ws, size_t ws_size,
                              hipStream_t stream) {
  const float* h        = (const float*)d_in[0];
  const float* W        = (const float*)d_in[1];
  const float* pre_bias = (const float*)d_in[2];
  const float* enc_bias = (const float*)d_in[3];
  float* C = (float*)d_out;

  const size_t a1_bytes = (size_t)N_TOKENS * D_MODEL * sizeof(_Float16);   // 50.3 MB
  const size_t b1_bytes = (size_t)D_SPARSE * D_MODEL * sizeof(_Float16);   // 151.0 MB
  if (ws_size < a1_bytes + b1_bytes) return;

  _Float16* A1 = (_Float16*)d_ws;
  _Float16* B1 = (_Float16*)((char*)d_ws + a1_bytes);
  int2* lists = (int2*)d_ws;                    // parked in A1's dead region

  convert_h_kernel<<<2048, 256, 0, stream>>>(h, pre_bias, A1);
  convert_w_kernel<<<4096, 256, 0, stream>>>(W, B1);
  gemm_kernel<<<(N_TOKENS/256) * (D_SPARSE/256), 512, 0, stream>>>(A1, B1, enc_bias, C);
  topk_select<<<N_TOKENS, 256, 0, stream>>>(C, h, pre_bias, W, enc_bias, lists);
  topk_write<<<N_TOKENS * (D_SPARSE/SEG), 256, 0, stream>>>(lists, C);
}